// Round 5
// baseline (830.215 us; speedup 1.0000x reference)
//
#include <hip/hip_runtime.h>
#include <hip/hip_bf16.h>

using bf16 = __hip_bfloat16;
typedef __attribute__((ext_vector_type(8))) short bf16x8;   // 8 bf16 in 4 VGPRs
typedef __attribute__((ext_vector_type(4))) short bf16x4;   // 4 bf16 in 2 VGPRs
typedef __attribute__((ext_vector_type(4))) float f32x4;

// async global->LDS, 16B per lane; LDS dest = wave-uniform base + lane*16
typedef const __attribute__((address_space(1))) void* as1_t;
typedef __attribute__((address_space(3))) void* as3_t;
__device__ __forceinline__ void load_lds16(const void* g, void* l) {
    __builtin_amdgcn_global_load_lds((as1_t)g, (as3_t)l, 16, 0, 0);
}

// ---------------- elementwise cast f32 -> bf16 (x) ----------------
__global__ __launch_bounds__(256) void cast_f32_bf16(const float* __restrict__ src,
                                                     bf16* __restrict__ dst, int n4) {
    int i = (blockIdx.x * 256 + threadIdx.x);
    if (i >= n4) return;
    const float4 v = *(const float4*)(src + (long)i * 4);
    bf16 t[4];
    t[0] = __float2bfloat16(v.x);
    t[1] = __float2bfloat16(v.y);
    t[2] = __float2bfloat16(v.z);
    t[3] = __float2bfloat16(v.w);
    *(uint2*)(dst + (long)i * 4) = *(uint2*)t;
}

// ---------------- tiled transpose-cast: src[K][N] f32 -> dst[N][K] bf16 ----------------
__global__ __launch_bounds__(256) void transpose_cast(const float* __restrict__ src,
                                                      int K, int N, bf16* __restrict__ dst) {
    __shared__ float tile[32][33];
    const int tx = threadIdx.x & 31;
    const int ty = threadIdx.x >> 5;   // 0..7
    const int n0 = blockIdx.x * 32;
    const int k0 = blockIdx.y * 32;
    for (int i = 0; i < 32; i += 8)
        tile[ty + i][tx] = src[(long)(k0 + ty + i) * N + n0 + tx];
    __syncthreads();
    for (int i = 0; i < 32; i += 8)
        dst[(long)(n0 + ty + i) * K + k0 + tx] = __float2bfloat16(tile[tx][ty + i]);
}

// ---------------- V transpose via LDS tile: qkv[8192][1536] -> vt[b][kvh][64][2048] ----------------
__global__ __launch_bounds__(256) void transpose_v(const bf16* __restrict__ qkv,
                                                   bf16* __restrict__ vt) {
    __shared__ bf16 tile[64][72];
    const int tb = blockIdx.x, kvh = blockIdx.y, b = blockIdx.z;
    const int r = threadIdx.x >> 3;          // 0..31
    const int c = (threadIdx.x & 7) * 8;     // 0..56
    const bf16* src = qkv + (long)(b * 2048 + tb * 64) * 1536 + 1280 + kvh * 64;
    *(uint4*)&tile[r][c]      = *(const uint4*)(src + (long)r * 1536 + c);
    *(uint4*)&tile[r + 32][c] = *(const uint4*)(src + (long)(r + 32) * 1536 + c);
    __syncthreads();
    bf16* dst = vt + (long)(b * 4 + kvh) * 64 * 2048 + tb * 64;
#pragma unroll
    for (int rr = 0; rr < 2; rr++) {
        const int d = r + rr * 32;
        bf16 t8[8];
#pragma unroll
        for (int e = 0; e < 8; e++) t8[e] = tile[c + e][d];
        *(uint4*)(dst + (long)d * 2048 + c) = *(uint4*)t8;
    }
}

// ---------------- GEMM (m97 structure): C[M][N] = A[M][K] * Bt[N][K]^T ----------------
template <bool BF16_OUT>
__global__ __launch_bounds__(256) void gemm_bt(const bf16* __restrict__ A,
                                               const bf16* __restrict__ Bt,
                                               void* __restrict__ C,
                                               int M, int N, int K) {
    __shared__ bf16 Ash[128 * 32];
    __shared__ bf16 Bsh[128 * 32];
    const int tid  = threadIdx.x;
    const int lane = tid & 63;
    const int wid  = tid >> 6;
    const int wm   = (wid >> 1) * 64;
    const int wn   = (wid & 1) * 64;
    const int quad = lane >> 4;
    const int l16  = lane & 15;
    const int bm = blockIdx.x, bn = blockIdx.y;

    const int r_l   = lane >> 2;                 // 0..15
    const int cslot = lane & 3;
    const int cdat  = (cslot - (r_l >> 1)) & 3;  // swizzled source chunk

    const bf16* pa0 = A  + (long)(bm * 128 + wid * 32 + r_l) * K + cdat * 8;
    const bf16* pa1 = pa0 + (long)16 * K;
    const bf16* pb0 = Bt + (long)(bn * 128 + wid * 32 + r_l) * K + cdat * 8;
    const bf16* pb1 = pb0 + (long)16 * K;
    bf16* la0 = Ash + (wid * 32) * 32;
    bf16* la1 = Ash + (wid * 32 + 16) * 32;
    bf16* lb0 = Bsh + (wid * 32) * 32;
    bf16* lb1 = Bsh + (wid * 32 + 16) * 32;

    const int sw = ((quad + (l16 >> 1)) & 3) * 8;   // swizzled chunk for frag reads

    f32x4 acc[4][4] = {};

    for (int k0 = 0; k0 < K; k0 += 32) {
        __syncthreads();
        load_lds16(pa0 + k0, la0);
        load_lds16(pa1 + k0, la1);
        load_lds16(pb0 + k0, lb0);
        load_lds16(pb1 + k0, lb1);
        __syncthreads();

        bf16x8 af[4], bfr[4];
#pragma unroll
        for (int i = 0; i < 4; i++) af[i]  = *(const bf16x8*)&Ash[(wm + i * 16 + l16) * 32 + sw];
#pragma unroll
        for (int j = 0; j < 4; j++) bfr[j] = *(const bf16x8*)&Bsh[(wn + j * 16 + l16) * 32 + sw];
#pragma unroll
        for (int i = 0; i < 4; i++)
#pragma unroll
            for (int j = 0; j < 4; j++)
                acc[i][j] = __builtin_amdgcn_mfma_f32_16x16x32_bf16(af[i], bfr[j], acc[i][j], 0, 0, 0);
    }

#pragma unroll
    for (int i = 0; i < 4; i++) {
#pragma unroll
        for (int r = 0; r < 4; r++) {
            const long row = (long)(bm * 128 + wm + i * 16 + quad * 4 + r);
#pragma unroll
            for (int j = 0; j < 4; j++) {
                const int col = bn * 128 + wn + j * 16 + l16;
                const float v = acc[i][j][r];
                if (BF16_OUT) ((bf16*)C)[row * N + col] = __float2bfloat16(v);
                else          ((float*)C)[row * N + col] = v;
            }
        }
    }
}

// ---------------- flash attention v5: zero-LDS, zero-barrier register streaming ----------------
// grid: (T/64, NH, B), 256 threads = 4 independent waves; wave owns 16 q rows.
// S^T = mfma(K_frag, Q_frag): K A-operand frags load DIRECTLY from global (16B/lane),
// V A-operand frags load DIRECTLY from vt (8B/lane). No LDS, no __syncthreads:
// waves are fully self-paced; latency hidden by TLP (no LDS -> max residency).
// Q pre-scaled by 1/sqrt(64)*log2(e) so p = exp2(s) with no per-element multiply.
__global__ __launch_bounds__(256) void attn_kernel(const bf16* __restrict__ qkv,
                                                   const bf16* __restrict__ vt,
                                                   bf16* __restrict__ attn) {
    const int tid  = threadIdx.x;
    const int lane = tid & 63;
    const int wid  = tid >> 6;
    const int quad = lane >> 4;
    const int l16  = lane & 15;
    const int h    = blockIdx.y;
    const int b    = blockIdx.z;
    const int kvh  = h >> 2;
    const int qblock = (gridDim.x - 1 - blockIdx.x) * 64;   // heavy blocks first
    const int q0     = qblock + wid * 16;

    const float ls = 0.125f * 1.44269504f;   // 1/sqrt(64) * log2(e)

    // Q fragment (B-operand for S^T): n=q=l16, k=d=kf*32+quad*8+j; pre-scaled by ls
    const bf16* qbase = qkv + (long)(b * 2048 + q0 + l16) * 1536 + h * 64;
    bf16x8 qf[2];
#pragma unroll
    for (int kf = 0; kf < 2; kf++) {
        const bf16* qp = qbase + kf * 32 + quad * 8;
        bf16 t8[8];
#pragma unroll
        for (int e = 0; e < 8; e++) t8[e] = __float2bfloat16(__bfloat162float(qp[e]) * ls);
        qf[kf] = *(const bf16x8*)t8;
    }

    f32x4 o[4] = {};          // O^T: q=l16, d = dt*16 + quad*4 + r
    float l_part = 0.f;       // per-lane softmax denominator (q = l16)

    const bf16* kg = qkv + (long)(b * 2048) * 1536 + 1024 + kvh * 64;
    const bf16* vg = vt + (long)(b * 4 + kvh) * 64 * 2048;

    const int nIter = qblock / 64 + 1;
    for (int it = 0; it < nIter; ++it) {
        const int kv0 = it * 64;

        // ---- S^T = K Q^T : s[kvt]: q=l16, kv = kv0 + kvt*16 + quad*4 + r ----
        f32x4 s[4] = {};
#pragma unroll
        for (int kvt = 0; kvt < 4; kvt++)
#pragma unroll
            for (int kf = 0; kf < 2; kf++) {
                const bf16x8 kfr = *(const bf16x8*)(kg + (long)(kv0 + kvt * 16 + l16) * 1536
                                                       + kf * 32 + quad * 8);
                s[kvt] = __builtin_amdgcn_mfma_f32_16x16x32_bf16(kfr, qf[kf], s[kvt], 0, 0, 0);
            }

        // ---- causal mask: only the last tile touches the diagonal ----
        if (it == nIter - 1) {
            const int qq = wid * 16 + l16;
#pragma unroll
            for (int kvt = 0; kvt < 4; kvt++)
#pragma unroll
                for (int r = 0; r < 4; r++)
                    if (kvt * 16 + quad * 4 + r > qq) s[kvt][r] = -1e30f;
        }

        // ---- p = exp2(s); accumulate l; P feeds PV mfma directly from registers ----
#pragma unroll
        for (int kvt = 0; kvt < 4; kvt++) {
            bf16 tp[4];
#pragma unroll
            for (int r = 0; r < 4; r++) {
                const float p = exp2f(s[kvt][r]);
                l_part += p;
                tp[r] = __float2bfloat16(p);
            }
            const bf16x4 pk = *(const bf16x4*)tp;   // B-operand: n=q=l16, k=kv=quad*4+j
#pragma unroll
            for (int dt = 0; dt < 4; dt++) {
                const bf16x4 vf = *(const bf16x4*)(vg + (long)(dt * 16 + l16) * 2048
                                                      + kv0 + kvt * 16 + quad * 4);
                o[dt] = __builtin_amdgcn_mfma_f32_16x16x16bf16_1k(vf, pk, o[dt], 0, 0, 0);
            }
        }
    }

    // ---- epilogue: reduce l across quads, normalize, store O^T ----
    float l_tot = l_part;
    l_tot += __shfl_xor(l_tot, 16, 64);
    l_tot += __shfl_xor(l_tot, 32, 64);
    const float inv = 1.f / l_tot;

    bf16* obase = attn + (long)(b * 2048 + q0 + l16) * 1024 + h * 64;
#pragma unroll
    for (int dt = 0; dt < 4; dt++) {
        bf16 t4[4];
#pragma unroll
        for (int r = 0; r < 4; r++) t4[r] = __float2bfloat16(o[dt][r] * inv);
        *(uint2*)(obase + dt * 16 + quad * 4) = *(uint2*)t4;
    }
}

// ---------------- launch ----------------
extern "C" void kernel_launch(void* const* d_in, const int* in_sizes, int n_in,
                              void* d_out, int out_size, void* d_ws, size_t ws_size,
                              hipStream_t stream) {
    const float* x  = (const float*)d_in[0];
    const float* wq = (const float*)d_in[1];
    const float* wk = (const float*)d_in[2];
    const float* wv = (const float*)d_in[3];
    const float* wo = (const float*)d_in[4];
    float* out = (float*)d_out;

    char* ws = (char*)d_ws;
    bf16* xb     = (bf16*)(ws);                       // 8192*1024
    bf16* wqkvT  = (bf16*)(ws + 16777216);            // 1536*1024
    bf16* woT    = (bf16*)(ws + 19922944);            // 1024*1024
    bf16* qkv    = (bf16*)(ws + 22020096);            // 8192*1536
    bf16* vt     = (bf16*)(ws + 47185920);            // 4*4*64*2048
    bf16* attn   = (bf16*)(ws + 51380224);            // 8192*1024

    cast_f32_bf16<<<8192, 256, 0, stream>>>(x, xb, 2097152);

    transpose_cast<<<dim3(32, 32), 256, 0, stream>>>(wq, 1024, 1024, wqkvT);
    transpose_cast<<<dim3(8, 32),  256, 0, stream>>>(wk, 1024, 256,  wqkvT + 1024 * 1024);
    transpose_cast<<<dim3(8, 32),  256, 0, stream>>>(wv, 1024, 256,  wqkvT + 1280 * 1024);
    transpose_cast<<<dim3(32, 32), 256, 0, stream>>>(wo, 1024, 1024, woT);

    gemm_bt<true><<<dim3(64, 12), 256, 0, stream>>>(xb, wqkvT, qkv, 8192, 1536, 1024);

    transpose_v<<<dim3(32, 4, 4), 256, 0, stream>>>(qkv, vt);

    attn_kernel<<<dim3(32, 16, 4), 256, 0, stream>>>(qkv, vt, attn);

    gemm_bt<false><<<dim3(64, 8), 256, 0, stream>>>(attn, woT, out, 8192, 1024, 1024);
}

// Round 6
// 286.603 us; speedup vs baseline: 2.8967x; 2.8967x over previous
//
#include <hip/hip_runtime.h>
#include <hip/hip_bf16.h>

using bf16 = __hip_bfloat16;
typedef __attribute__((ext_vector_type(8))) short bf16x8;   // 8 bf16 in 4 VGPRs
typedef __attribute__((ext_vector_type(4))) short bf16x4;   // 4 bf16 in 2 VGPRs
typedef __attribute__((ext_vector_type(4))) float f32x4;

// async global->LDS, 16B per lane; LDS dest = wave-uniform base + lane*16
typedef const __attribute__((address_space(1))) void* as1_t;
typedef __attribute__((address_space(3))) void* as3_t;
__device__ __forceinline__ void load_lds16(const void* g, void* l) {
    __builtin_amdgcn_global_load_lds((as1_t)g, (as3_t)l, 16, 0, 0);
}

// ---------------- elementwise cast f32 -> bf16 (x) ----------------
__global__ __launch_bounds__(256) void cast_f32_bf16(const float* __restrict__ src,
                                                     bf16* __restrict__ dst, int n4) {
    int i = (blockIdx.x * 256 + threadIdx.x);
    if (i >= n4) return;
    const float4 v = *(const float4*)(src + (long)i * 4);
    bf16 t[4];
    t[0] = __float2bfloat16(v.x);
    t[1] = __float2bfloat16(v.y);
    t[2] = __float2bfloat16(v.z);
    t[3] = __float2bfloat16(v.w);
    *(uint2*)(dst + (long)i * 4) = *(uint2*)t;
}

// ---------------- tiled transpose-cast: src[K][N] f32 -> dst[N][K] bf16 ----------------
__global__ __launch_bounds__(256) void transpose_cast(const float* __restrict__ src,
                                                      int K, int N, bf16* __restrict__ dst) {
    __shared__ float tile[32][33];
    const int tx = threadIdx.x & 31;
    const int ty = threadIdx.x >> 5;   // 0..7
    const int n0 = blockIdx.x * 32;
    const int k0 = blockIdx.y * 32;
    for (int i = 0; i < 32; i += 8)
        tile[ty + i][tx] = src[(long)(k0 + ty + i) * N + n0 + tx];
    __syncthreads();
    for (int i = 0; i < 32; i += 8)
        dst[(long)(n0 + ty + i) * K + k0 + tx] = __float2bfloat16(tile[tx][ty + i]);
}

// ---------------- V transpose via LDS tile: qkv[8192][1536] -> vt[b][kvh][64][2048] ----------------
__global__ __launch_bounds__(256) void transpose_v(const bf16* __restrict__ qkv,
                                                   bf16* __restrict__ vt) {
    __shared__ bf16 tile[64][72];
    const int tb = blockIdx.x, kvh = blockIdx.y, b = blockIdx.z;
    const int r = threadIdx.x >> 3;          // 0..31
    const int c = (threadIdx.x & 7) * 8;     // 0..56
    const bf16* src = qkv + (long)(b * 2048 + tb * 64) * 1536 + 1280 + kvh * 64;
    *(uint4*)&tile[r][c]      = *(const uint4*)(src + (long)r * 1536 + c);
    *(uint4*)&tile[r + 32][c] = *(const uint4*)(src + (long)(r + 32) * 1536 + c);
    __syncthreads();
    bf16* dst = vt + (long)(b * 4 + kvh) * 64 * 2048 + tb * 64;
#pragma unroll
    for (int rr = 0; rr < 2; rr++) {
        const int d = r + rr * 32;
        bf16 t8[8];
#pragma unroll
        for (int e = 0; e < 8; e++) t8[e] = tile[c + e][d];
        *(uint4*)(dst + (long)d * 2048 + c) = *(uint4*)t8;
    }
}

// ---------------- GEMM (m97 structure): C[M][N] = A[M][K] * Bt[N][K]^T ----------------
template <bool BF16_OUT>
__global__ __launch_bounds__(256) void gemm_bt(const bf16* __restrict__ A,
                                               const bf16* __restrict__ Bt,
                                               void* __restrict__ C,
                                               int M, int N, int K) {
    __shared__ bf16 Ash[128 * 32];
    __shared__ bf16 Bsh[128 * 32];
    const int tid  = threadIdx.x;
    const int lane = tid & 63;
    const int wid  = tid >> 6;
    const int wm   = (wid >> 1) * 64;
    const int wn   = (wid & 1) * 64;
    const int quad = lane >> 4;
    const int l16  = lane & 15;
    const int bm = blockIdx.x, bn = blockIdx.y;

    const int r_l   = lane >> 2;                 // 0..15
    const int cslot = lane & 3;
    const int cdat  = (cslot - (r_l >> 1)) & 3;  // swizzled source chunk

    const bf16* pa0 = A  + (long)(bm * 128 + wid * 32 + r_l) * K + cdat * 8;
    const bf16* pa1 = pa0 + (long)16 * K;
    const bf16* pb0 = Bt + (long)(bn * 128 + wid * 32 + r_l) * K + cdat * 8;
    const bf16* pb1 = pb0 + (long)16 * K;
    bf16* la0 = Ash + (wid * 32) * 32;
    bf16* la1 = Ash + (wid * 32 + 16) * 32;
    bf16* lb0 = Bsh + (wid * 32) * 32;
    bf16* lb1 = Bsh + (wid * 32 + 16) * 32;

    const int sw = ((quad + (l16 >> 1)) & 3) * 8;   // swizzled chunk for frag reads

    f32x4 acc[4][4] = {};

    for (int k0 = 0; k0 < K; k0 += 32) {
        __syncthreads();
        load_lds16(pa0 + k0, la0);
        load_lds16(pa1 + k0, la1);
        load_lds16(pb0 + k0, lb0);
        load_lds16(pb1 + k0, lb1);
        __syncthreads();

        bf16x8 af[4], bfr[4];
#pragma unroll
        for (int i = 0; i < 4; i++) af[i]  = *(const bf16x8*)&Ash[(wm + i * 16 + l16) * 32 + sw];
#pragma unroll
        for (int j = 0; j < 4; j++) bfr[j] = *(const bf16x8*)&Bsh[(wn + j * 16 + l16) * 32 + sw];
#pragma unroll
        for (int i = 0; i < 4; i++)
#pragma unroll
            for (int j = 0; j < 4; j++)
                acc[i][j] = __builtin_amdgcn_mfma_f32_16x16x32_bf16(af[i], bfr[j], acc[i][j], 0, 0, 0);
    }

#pragma unroll
    for (int i = 0; i < 4; i++) {
#pragma unroll
        for (int r = 0; r < 4; r++) {
            const long row = (long)(bm * 128 + wm + i * 16 + quad * 4 + r);
#pragma unroll
            for (int j = 0; j < 4; j++) {
                const int col = bn * 128 + wn + j * 16 + l16;
                const float v = acc[i][j][r];
                if (BF16_OUT) ((bf16*)C)[row * N + col] = __float2bfloat16(v);
                else          ((float*)C)[row * N + col] = v;
            }
        }
    }
}

// ---------------- flash attention v6: v3 structure + reg-prefetch pipeline + VALU diet ----------------
// grid: (T/64, NH, B), 256 threads = 4 waves; wave owns 16 q rows. kv-tile 64 in LDS.
// S^T = mfma(K_frag, Q_frag); P stays in registers (B-operand of 16x16x16 PV mfma).
// l computed by an extra MFMA with A=ones (matrix pipe, not VALU); Q pre-scaled so p=exp2(s).
// Tile it+1 is prefetched into VGPRs BEFORE computing tile it (hides global latency).
__global__ __launch_bounds__(256) void attn_kernel(const bf16* __restrict__ qkv,
                                                   const bf16* __restrict__ vt,
                                                   bf16* __restrict__ attn) {
    __shared__ bf16 Ksh[64][72];      // [kv][d]
    __shared__ bf16 Vsh[64][72];      // [d][kv]

    const int tid  = threadIdx.x;
    const int lane = tid & 63;
    const int wid  = tid >> 6;
    const int quad = lane >> 4;
    const int l16  = lane & 15;
    const int h    = blockIdx.y;
    const int b    = blockIdx.z;
    const int kvh  = h >> 2;
    const int qblock = (gridDim.x - 1 - blockIdx.x) * 64;   // heavy blocks first
    const int q0     = qblock + wid * 16;

    const float ls = 0.125f * 1.44269504f;   // 1/sqrt(64) * log2(e)

    // Q fragment (B-operand for S^T): n=q=l16, k=d=kf*32+quad*8+j; pre-scaled by ls
    const bf16* qbase = qkv + (long)(b * 2048 + q0 + l16) * 1536 + h * 64;
    bf16x8 qf[2];
#pragma unroll
    for (int kf = 0; kf < 2; kf++) {
        const bf16* qp = qbase + kf * 32 + quad * 8;
        bf16 t8[8];
#pragma unroll
        for (int e = 0; e < 8; e++) t8[e] = __float2bfloat16(__bfloat162float(qp[e]) * ls);
        qf[kf] = *(const bf16x8*)t8;
    }

    // ones fragment for l-accumulation MFMA (A[m][k] = 1.0)
    bf16x4 ones;
    { short o1 = (short)0x3F80; short t4[4] = {o1, o1, o1, o1}; ones = *(const bf16x4*)t4; }

    f32x4 o[4] = {};          // O^T: q=l16, d = dt*16 + quad*4 + r
    f32x4 ol = {};            // l accumulator: every element = sum_kv P[kv][q=l16]

    const bf16* kg = qkv + (long)(b * 2048) * 1536 + 1024 + kvh * 64;
    const bf16* vg = vt + (long)(b * 4 + kvh) * 64 * 2048;
    const int r0 = tid >> 3;          // 0..31
    const int c0 = (tid & 7) * 8;     // 0..56

    // staging source pointers (advance per iter)
    const bf16* kp0 = kg + (long)r0 * 1536 + c0;
    const bf16* kp1 = kp0 + (long)32 * 1536;
    const bf16* vp0 = vg + (long)r0 * 2048 + c0;
    const bf16* vp1 = vp0 + (long)32 * 2048;

    // prologue: prefetch tile 0
    uint4 kr0 = *(const uint4*)kp0;
    uint4 kr1 = *(const uint4*)kp1;
    uint4 vr0 = *(const uint4*)vp0;
    uint4 vr1 = *(const uint4*)vp1;

    const int nIter = qblock / 64 + 1;
    for (int it = 0; it < nIter; ++it) {
        __syncthreads();   // WAR: prior iter LDS reads done
        *(uint4*)&Ksh[r0][c0]      = kr0;
        *(uint4*)&Ksh[r0 + 32][c0] = kr1;
        *(uint4*)&Vsh[r0][c0]      = vr0;
        *(uint4*)&Vsh[r0 + 32][c0] = vr1;
        __syncthreads();

        // ---- prefetch tile it+1 (latency hides under compute below) ----
        if (it + 1 < nIter) {
            const long ko = (long)(it + 1) * 64 * 1536;
            const long vo = (it + 1) * 64;
            kr0 = *(const uint4*)(kp0 + ko);
            kr1 = *(const uint4*)(kp1 + ko);
            vr0 = *(const uint4*)(vp0 + vo);
            vr1 = *(const uint4*)(vp1 + vo);
        }

        // ---- S^T = K Q^T : s[kvt]: q=l16, kv = it*64 + kvt*16 + quad*4 + r ----
        f32x4 s[4] = {};
#pragma unroll
        for (int kvt = 0; kvt < 4; kvt++)
#pragma unroll
            for (int kf = 0; kf < 2; kf++) {
                const bf16x8 kfr = *(const bf16x8*)&Ksh[kvt * 16 + l16][kf * 32 + quad * 8];
                s[kvt] = __builtin_amdgcn_mfma_f32_16x16x32_bf16(kfr, qf[kf], s[kvt], 0, 0, 0);
            }

        // ---- causal mask: only the last tile touches the diagonal ----
        if (it == nIter - 1) {
            const int qq = wid * 16 + l16;
#pragma unroll
            for (int kvt = 0; kvt < 4; kvt++)
#pragma unroll
                for (int r = 0; r < 4; r++)
                    if (kvt * 16 + quad * 4 + r > qq) s[kvt][r] = -1e30f;
        }

        // ---- p = exp2(s) (Q pre-scaled); packed cvt; PV + l both on matrix pipe ----
#pragma unroll
        for (int kvt = 0; kvt < 4; kvt++) {
            float2 p01, p23;
            p01.x = exp2f(s[kvt][0]);
            p01.y = exp2f(s[kvt][1]);
            p23.x = exp2f(s[kvt][2]);
            p23.y = exp2f(s[kvt][3]);
            __hip_bfloat162 pk01 = __float22bfloat162_rn(p01);
            __hip_bfloat162 pk23 = __float22bfloat162_rn(p23);
            bf16x4 pk;
            *(__hip_bfloat162*)&pk       = pk01;
            *((__hip_bfloat162*)&pk + 1) = pk23;

            ol = __builtin_amdgcn_mfma_f32_16x16x16bf16_1k(ones, pk, ol, 0, 0, 0);
#pragma unroll
            for (int dt = 0; dt < 4; dt++) {
                const bf16x4 vf = *(const bf16x4*)&Vsh[dt * 16 + l16][kvt * 16 + quad * 4];
                o[dt] = __builtin_amdgcn_mfma_f32_16x16x16bf16_1k(vf, pk, o[dt], 0, 0, 0);
            }
        }
    }

    // ---- epilogue: l is complete per-lane (MFMA summed over kv); normalize + store ----
    const float inv = 1.f / ol[0];
    bf16* obase = attn + (long)(b * 2048 + q0 + l16) * 1024 + h * 64;
#pragma unroll
    for (int dt = 0; dt < 4; dt++) {
        bf16 t4[4];
#pragma unroll
        for (int r = 0; r < 4; r++) t4[r] = __float2bfloat16(o[dt][r] * inv);
        *(uint2*)(obase + dt * 16 + quad * 4) = *(uint2*)t4;
    }
}

// ---------------- launch ----------------
extern "C" void kernel_launch(void* const* d_in, const int* in_sizes, int n_in,
                              void* d_out, int out_size, void* d_ws, size_t ws_size,
                              hipStream_t stream) {
    const float* x  = (const float*)d_in[0];
    const float* wq = (const float*)d_in[1];
    const float* wk = (const float*)d_in[2];
    const float* wv = (const float*)d_in[3];
    const float* wo = (const float*)d_in[4];
    float* out = (float*)d_out;

    char* ws = (char*)d_ws;
    bf16* xb     = (bf16*)(ws);                       // 8192*1024
    bf16* wqkvT  = (bf16*)(ws + 16777216);            // 1536*1024
    bf16* woT    = (bf16*)(ws + 19922944);            // 1024*1024
    bf16* qkv    = (bf16*)(ws + 22020096);            // 8192*1536
    bf16* vt     = (bf16*)(ws + 47185920);            // 4*4*64*2048
    bf16* attn   = (bf16*)(ws + 51380224);            // 8192*1024

    cast_f32_bf16<<<8192, 256, 0, stream>>>(x, xb, 2097152);

    transpose_cast<<<dim3(32, 32), 256, 0, stream>>>(wq, 1024, 1024, wqkvT);
    transpose_cast<<<dim3(8, 32),  256, 0, stream>>>(wk, 1024, 256,  wqkvT + 1024 * 1024);
    transpose_cast<<<dim3(8, 32),  256, 0, stream>>>(wv, 1024, 256,  wqkvT + 1280 * 1024);
    transpose_cast<<<dim3(32, 32), 256, 0, stream>>>(wo, 1024, 1024, woT);

    gemm_bt<true><<<dim3(64, 12), 256, 0, stream>>>(xb, wqkvT, qkv, 8192, 1536, 1024);

    transpose_v<<<dim3(32, 4, 4), 256, 0, stream>>>(qkv, vt);

    attn_kernel<<<dim3(32, 16, 4), 256, 0, stream>>>(qkv, vt, attn);

    gemm_bt<false><<<dim3(64, 8), 256, 0, stream>>>(attn, woT, out, 8192, 1024, 1024);
}

// Round 7
// 236.752 us; speedup vs baseline: 3.5067x; 1.2106x over previous
//
#include <hip/hip_runtime.h>
#include <hip/hip_bf16.h>

using bf16 = __hip_bfloat16;
typedef __attribute__((ext_vector_type(8))) short bf16x8;   // 8 bf16 in 4 VGPRs
typedef __attribute__((ext_vector_type(4))) short bf16x4;   // 4 bf16 in 2 VGPRs
typedef __attribute__((ext_vector_type(4))) float f32x4;

// async global->LDS, 16B per lane; LDS dest = wave-uniform base + lane*16
typedef const __attribute__((address_space(1))) void* as1_t;
typedef __attribute__((address_space(3))) void* as3_t;
__device__ __forceinline__ void load_lds16(const void* g, void* l) {
    __builtin_amdgcn_global_load_lds((as1_t)g, (as3_t)l, 16, 0, 0);
}

// ---------------- elementwise cast f32 -> bf16 (x) ----------------
__global__ __launch_bounds__(256) void cast_f32_bf16(const float* __restrict__ src,
                                                     bf16* __restrict__ dst, int n4) {
    int i = (blockIdx.x * 256 + threadIdx.x);
    if (i >= n4) return;
    const float4 v = *(const float4*)(src + (long)i * 4);
    bf16 t[4];
    t[0] = __float2bfloat16(v.x);
    t[1] = __float2bfloat16(v.y);
    t[2] = __float2bfloat16(v.z);
    t[3] = __float2bfloat16(v.w);
    *(uint2*)(dst + (long)i * 4) = *(uint2*)t;
}

// ---------------- tiled transpose-cast: src[K][N] f32 -> dst[N][K] bf16 ----------------
__global__ __launch_bounds__(256) void transpose_cast(const float* __restrict__ src,
                                                      int K, int N, bf16* __restrict__ dst) {
    __shared__ float tile[32][33];
    const int tx = threadIdx.x & 31;
    const int ty = threadIdx.x >> 5;   // 0..7
    const int n0 = blockIdx.x * 32;
    const int k0 = blockIdx.y * 32;
    for (int i = 0; i < 32; i += 8)
        tile[ty + i][tx] = src[(long)(k0 + ty + i) * N + n0 + tx];
    __syncthreads();
    for (int i = 0; i < 32; i += 8)
        dst[(long)(n0 + ty + i) * K + k0 + tx] = __float2bfloat16(tile[tx][ty + i]);
}

// ---------------- V transpose via LDS tile: qkv[8192][1536] -> vt[b][kvh][64][2048] ----------------
__global__ __launch_bounds__(256) void transpose_v(const bf16* __restrict__ qkv,
                                                   bf16* __restrict__ vt) {
    __shared__ bf16 tile[64][72];
    const int tb = blockIdx.x, kvh = blockIdx.y, b = blockIdx.z;
    const int r = threadIdx.x >> 3;          // 0..31
    const int c = (threadIdx.x & 7) * 8;     // 0..56
    const bf16* src = qkv + (long)(b * 2048 + tb * 64) * 1536 + 1280 + kvh * 64;
    *(uint4*)&tile[r][c]      = *(const uint4*)(src + (long)r * 1536 + c);
    *(uint4*)&tile[r + 32][c] = *(const uint4*)(src + (long)(r + 32) * 1536 + c);
    __syncthreads();
    bf16* dst = vt + (long)(b * 4 + kvh) * 64 * 2048 + tb * 64;
#pragma unroll
    for (int rr = 0; rr < 2; rr++) {
        const int d = r + rr * 32;
        bf16 t8[8];
#pragma unroll
        for (int e = 0; e < 8; e++) t8[e] = tile[c + e][d];
        *(uint4*)(dst + (long)d * 2048 + c) = *(uint4*)t8;
    }
}

// ---------------- GEMM (m97 structure): C[M][N] = A[M][K] * Bt[N][K]^T ----------------
template <bool BF16_OUT>
__global__ __launch_bounds__(256) void gemm_bt(const bf16* __restrict__ A,
                                               const bf16* __restrict__ Bt,
                                               void* __restrict__ C,
                                               int M, int N, int K) {
    __shared__ bf16 Ash[128 * 32];
    __shared__ bf16 Bsh[128 * 32];
    const int tid  = threadIdx.x;
    const int lane = tid & 63;
    const int wid  = tid >> 6;
    const int wm   = (wid >> 1) * 64;
    const int wn   = (wid & 1) * 64;
    const int quad = lane >> 4;
    const int l16  = lane & 15;
    const int bm = blockIdx.x, bn = blockIdx.y;

    const int r_l   = lane >> 2;                 // 0..15
    const int cslot = lane & 3;
    const int cdat  = (cslot - (r_l >> 1)) & 3;  // swizzled source chunk

    const bf16* pa0 = A  + (long)(bm * 128 + wid * 32 + r_l) * K + cdat * 8;
    const bf16* pa1 = pa0 + (long)16 * K;
    const bf16* pb0 = Bt + (long)(bn * 128 + wid * 32 + r_l) * K + cdat * 8;
    const bf16* pb1 = pb0 + (long)16 * K;
    bf16* la0 = Ash + (wid * 32) * 32;
    bf16* la1 = Ash + (wid * 32 + 16) * 32;
    bf16* lb0 = Bsh + (wid * 32) * 32;
    bf16* lb1 = Bsh + (wid * 32 + 16) * 32;

    const int sw = ((quad + (l16 >> 1)) & 3) * 8;   // swizzled chunk for frag reads

    f32x4 acc[4][4] = {};

    for (int k0 = 0; k0 < K; k0 += 32) {
        __syncthreads();
        load_lds16(pa0 + k0, la0);
        load_lds16(pa1 + k0, la1);
        load_lds16(pb0 + k0, lb0);
        load_lds16(pb1 + k0, lb1);
        __syncthreads();

        bf16x8 af[4], bfr[4];
#pragma unroll
        for (int i = 0; i < 4; i++) af[i]  = *(const bf16x8*)&Ash[(wm + i * 16 + l16) * 32 + sw];
#pragma unroll
        for (int j = 0; j < 4; j++) bfr[j] = *(const bf16x8*)&Bsh[(wn + j * 16 + l16) * 32 + sw];
#pragma unroll
        for (int i = 0; i < 4; i++)
#pragma unroll
            for (int j = 0; j < 4; j++)
                acc[i][j] = __builtin_amdgcn_mfma_f32_16x16x32_bf16(af[i], bfr[j], acc[i][j], 0, 0, 0);
    }

#pragma unroll
    for (int i = 0; i < 4; i++) {
#pragma unroll
        for (int r = 0; r < 4; r++) {
            const long row = (long)(bm * 128 + wm + i * 16 + quad * 4 + r);
#pragma unroll
            for (int j = 0; j < 4; j++) {
                const int col = bn * 128 + wn + j * 16 + l16;
                const float v = acc[i][j][r];
                if (BF16_OUT) ((bf16*)C)[row * N + col] = __float2bfloat16(v);
                else          ((float*)C)[row * N + col] = v;
            }
        }
    }
}

// ---------------- flash attention v7: v6 + perfectly balanced q-block pairing ----------------
// grid: (T/128, NH, B) = (16,16,4); 256 threads = 4 waves; wave owns 16 q rows.
// Each block processes TWO q-blocks {31-pb, pb}: (32-pb) + (pb+1) = 33 tile-iters
// for every block -> zero causal imbalance, occupancy sustained to the end.
// S^T = mfma(K_frag, Q_frag); P stays in registers; l via ones-MFMA (matrix pipe);
// Q pre-scaled so p=exp2(s); next tile reg-prefetched before compute.
__global__ __launch_bounds__(256) void attn_kernel(const bf16* __restrict__ qkv,
                                                   const bf16* __restrict__ vt,
                                                   bf16* __restrict__ attn) {
    __shared__ bf16 Ksh[64][72];      // [kv][d]
    __shared__ bf16 Vsh[64][72];      // [d][kv]

    const int tid  = threadIdx.x;
    const int lane = tid & 63;
    const int wid  = tid >> 6;
    const int quad = lane >> 4;
    const int l16  = lane & 15;
    const int h    = blockIdx.y;
    const int b    = blockIdx.z;
    const int kvh  = h >> 2;
    const int pb   = blockIdx.x;      // 0..15

    const float ls = 0.125f * 1.44269504f;   // 1/sqrt(64) * log2(e)

    // ones fragment for l-accumulation MFMA (A[m][k] = 1.0)
    bf16x4 ones;
    { short o1 = (short)0x3F80; short t4[4] = {o1, o1, o1, o1}; ones = *(const bf16x4*)t4; }

    const bf16* kg = qkv + (long)(b * 2048) * 1536 + 1024 + kvh * 64;
    const bf16* vg = vt + (long)(b * 4 + kvh) * 64 * 2048;
    const int r0 = tid >> 3;          // 0..31
    const int c0 = (tid & 7) * 8;     // 0..56

    const bf16* kp0 = kg + (long)r0 * 1536 + c0;
    const bf16* kp1 = kp0 + (long)32 * 1536;
    const bf16* vp0 = vg + (long)r0 * 2048 + c0;
    const bf16* vp1 = vp0 + (long)32 * 2048;

#pragma unroll 1
    for (int seg = 0; seg < 2; ++seg) {
        const int qb     = seg ? pb : (31 - pb);
        const int qblock = qb * 64;
        const int q0     = qblock + wid * 16;

        // Q fragment (B-operand for S^T): n=q=l16, k=d=kf*32+quad*8+j; pre-scaled by ls
        const bf16* qbase = qkv + (long)(b * 2048 + q0 + l16) * 1536 + h * 64;
        bf16x8 qf[2];
#pragma unroll
        for (int kf = 0; kf < 2; kf++) {
            const bf16* qp = qbase + kf * 32 + quad * 8;
            bf16 t8[8];
#pragma unroll
            for (int e = 0; e < 8; e++) t8[e] = __float2bfloat16(__bfloat162float(qp[e]) * ls);
            qf[kf] = *(const bf16x8*)t8;
        }

        f32x4 o[4] = {};          // O^T: q=l16, d = dt*16 + quad*4 + r
        f32x4 ol = {};            // l accumulator: every element = sum_kv P[kv][q=l16]

        // prologue: prefetch tile 0 of this segment
        uint4 kr0 = *(const uint4*)kp0;
        uint4 kr1 = *(const uint4*)kp1;
        uint4 vr0 = *(const uint4*)vp0;
        uint4 vr1 = *(const uint4*)vp1;

        const int nIter = qb + 1;
        for (int it = 0; it < nIter; ++it) {
            __syncthreads();   // WAR: prior iter (or prior segment) LDS reads done
            *(uint4*)&Ksh[r0][c0]      = kr0;
            *(uint4*)&Ksh[r0 + 32][c0] = kr1;
            *(uint4*)&Vsh[r0][c0]      = vr0;
            *(uint4*)&Vsh[r0 + 32][c0] = vr1;
            __syncthreads();

            // ---- prefetch tile it+1 (hides under compute below) ----
            if (it + 1 < nIter) {
                const long ko = (long)(it + 1) * 64 * 1536;
                const long vo = (it + 1) * 64;
                kr0 = *(const uint4*)(kp0 + ko);
                kr1 = *(const uint4*)(kp1 + ko);
                vr0 = *(const uint4*)(vp0 + vo);
                vr1 = *(const uint4*)(vp1 + vo);
            }

            // ---- S^T = K Q^T : s[kvt]: q=l16, kv = it*64 + kvt*16 + quad*4 + r ----
            f32x4 s[4] = {};
#pragma unroll
            for (int kvt = 0; kvt < 4; kvt++)
#pragma unroll
                for (int kf = 0; kf < 2; kf++) {
                    const bf16x8 kfr = *(const bf16x8*)&Ksh[kvt * 16 + l16][kf * 32 + quad * 8];
                    s[kvt] = __builtin_amdgcn_mfma_f32_16x16x32_bf16(kfr, qf[kf], s[kvt], 0, 0, 0);
                }

            // ---- causal mask: only the diagonal tile ----
            if (it == nIter - 1) {
                const int qq = wid * 16 + l16;
#pragma unroll
                for (int kvt = 0; kvt < 4; kvt++)
#pragma unroll
                    for (int r = 0; r < 4; r++)
                        if (kvt * 16 + quad * 4 + r > qq) s[kvt][r] = -1e30f;
            }

            // ---- p = exp2(s); packed cvt; PV + l on matrix pipe ----
#pragma unroll
            for (int kvt = 0; kvt < 4; kvt++) {
                float2 p01, p23;
                p01.x = exp2f(s[kvt][0]);
                p01.y = exp2f(s[kvt][1]);
                p23.x = exp2f(s[kvt][2]);
                p23.y = exp2f(s[kvt][3]);
                __hip_bfloat162 pk01 = __float22bfloat162_rn(p01);
                __hip_bfloat162 pk23 = __float22bfloat162_rn(p23);
                bf16x4 pk;
                *(__hip_bfloat162*)&pk       = pk01;
                *((__hip_bfloat162*)&pk + 1) = pk23;

                ol = __builtin_amdgcn_mfma_f32_16x16x16bf16_1k(ones, pk, ol, 0, 0, 0);
#pragma unroll
                for (int dt = 0; dt < 4; dt++) {
                    const bf16x4 vf = *(const bf16x4*)&Vsh[dt * 16 + l16][kvt * 16 + quad * 4];
                    o[dt] = __builtin_amdgcn_mfma_f32_16x16x16bf16_1k(vf, pk, o[dt], 0, 0, 0);
                }
            }
        }

        // ---- epilogue: l complete per-lane; normalize + store O^T ----
        const float inv = 1.f / ol[0];
        bf16* obase = attn + (long)(b * 2048 + q0 + l16) * 1024 + h * 64;
#pragma unroll
        for (int dt = 0; dt < 4; dt++) {
            bf16 t4[4];
#pragma unroll
            for (int r = 0; r < 4; r++) t4[r] = __float2bfloat16(o[dt][r] * inv);
            *(uint2*)(obase + dt * 16 + quad * 4) = *(uint2*)t4;
        }
    }
}

// ---------------- launch ----------------
extern "C" void kernel_launch(void* const* d_in, const int* in_sizes, int n_in,
                              void* d_out, int out_size, void* d_ws, size_t ws_size,
                              hipStream_t stream) {
    const float* x  = (const float*)d_in[0];
    const float* wq = (const float*)d_in[1];
    const float* wk = (const float*)d_in[2];
    const float* wv = (const float*)d_in[3];
    const float* wo = (const float*)d_in[4];
    float* out = (float*)d_out;

    char* ws = (char*)d_ws;
    bf16* xb     = (bf16*)(ws);                       // 8192*1024
    bf16* wqkvT  = (bf16*)(ws + 16777216);            // 1536*1024
    bf16* woT    = (bf16*)(ws + 19922944);            // 1024*1024
    bf16* qkv    = (bf16*)(ws + 22020096);            // 8192*1536
    bf16* vt     = (bf16*)(ws + 47185920);            // 4*4*64*2048
    bf16* attn   = (bf16*)(ws + 51380224);            // 8192*1024

    cast_f32_bf16<<<8192, 256, 0, stream>>>(x, xb, 2097152);

    transpose_cast<<<dim3(32, 32), 256, 0, stream>>>(wq, 1024, 1024, wqkvT);
    transpose_cast<<<dim3(8, 32),  256, 0, stream>>>(wk, 1024, 256,  wqkvT + 1024 * 1024);
    transpose_cast<<<dim3(8, 32),  256, 0, stream>>>(wv, 1024, 256,  wqkvT + 1280 * 1024);
    transpose_cast<<<dim3(32, 32), 256, 0, stream>>>(wo, 1024, 1024, woT);

    gemm_bt<true><<<dim3(64, 12), 256, 0, stream>>>(xb, wqkvT, qkv, 8192, 1536, 1024);

    transpose_v<<<dim3(32, 4, 4), 256, 0, stream>>>(qkv, vt);

    attn_kernel<<<dim3(16, 16, 4), 256, 0, stream>>>(qkv, vt, attn);

    gemm_bt<false><<<dim3(64, 8), 256, 0, stream>>>(attn, woT, out, 8192, 1024, 1024);
}